// Round 6
// baseline (88.398 us; speedup 1.0000x reference)
//
#include <hip/hip_runtime.h>

typedef __attribute__((ext_vector_type(8))) short short8;
typedef __attribute__((ext_vector_type(4))) float f32x4;

#define NRELROWS 502
#define NB 2048
#define DD 128
#define OUT_HALF (NB * DD)

__device__ __forceinline__ short f2bf(float x) {
    union { float f; unsigned u; } c; c.f = x;
    return (short)((c.u + 0x7FFFu + ((c.u >> 16) & 1u)) >> 16);
}

// Precompute: U[r][d] = sum_f rel[r][f]*W1[d][f]
//             V[r][d] = sum_f rel[r][f]*W1[d][128+f] + b1[d]
//             W2f = W2^T packed in MFMA B-fragment order, bf16
__global__ __launch_bounds__(256) void precompute_kernel(
    const float* __restrict__ rel, const float* __restrict__ W1,
    const float* __restrict__ b1, const float* __restrict__ W2,
    float* __restrict__ U, float* __restrict__ V,
    unsigned short* __restrict__ W2f)
{
    const int bid = blockIdx.x;
    const int tid = threadIdx.x;
    if (bid < 126) {
        __shared__ float srel[4][DD];
        const int r0 = bid << 2;
        for (int i = tid; i < 512; i += 256) {
            const int r = i >> 7, c = i & 127;
            const int rr = r0 + r;
            srel[r][c] = (rr < NRELROWS) ? rel[rr * DD + c] : 0.f;
        }
        __syncthreads();
        const int half = tid >> 7;      // 0 -> U, 1 -> V
        const int d = tid & 127;
        const float* wrow = W1 + d * 256 + half * 128;
        float a0 = 0.f, a1 = 0.f, a2 = 0.f, a3 = 0.f;
#pragma unroll 8
        for (int f = 0; f < 128; f += 4) {
            const float4 wv = *(const float4*)(wrow + f);
            a0 += srel[0][f]*wv.x + srel[0][f+1]*wv.y + srel[0][f+2]*wv.z + srel[0][f+3]*wv.w;
            a1 += srel[1][f]*wv.x + srel[1][f+1]*wv.y + srel[1][f+2]*wv.z + srel[1][f+3]*wv.w;
            a2 += srel[2][f]*wv.x + srel[2][f+1]*wv.y + srel[2][f+2]*wv.z + srel[2][f+3]*wv.w;
            a3 += srel[3][f]*wv.x + srel[3][f+1]*wv.y + srel[3][f+2]*wv.z + srel[3][f+3]*wv.w;
        }
        float res[4] = {a0, a1, a2, a3};
        const float bb = half ? b1[d] : 0.f;
#pragma unroll
        for (int r = 0; r < 4; ++r) {
            if (r0 + r < NRELROWS) {
                if (half) V[(r0 + r) * DD + d] = res[r] + bb;
                else      U[(r0 + r) * DD + d] = res[r];
            }
        }
    } else {
        // B-fragment packing: tile = kt*8+nt; within tile: lane l, slot i
        // B[f][n] with n = nt*16+(l&15), f = kt*32+(l>>4)*8+i, value = W2[n][f]
        const int tile = bid - 126;   // 0..31
        const int kt = tile >> 3, nt = tile & 7;
#pragma unroll
        for (int e = 0; e < 2; ++e) {
            const int within = tid * 2 + e;          // 0..511
            const int l = within >> 3, i = within & 7;
            const int n = nt * 16 + (l & 15);
            const int f = kt * 32 + (l >> 4) * 8 + i;
            W2f[tile * 512 + within] = (unsigned short)f2bf(W2[n * 128 + f]);
        }
    }
}

// Main: one block (256 thr, 4 waves) per query. Wave w does rows [32w,32w+32)
// in 2 passes of one 16-row MFMA tile each. h_t / r_t gathered straight into
// registers in C/D fragment layout (no LDS staging, no DMA serialization).
// Per pass issue order (sched_barrier-fenced): U/V -> af -> 64 gathers ->
// MFMA (B from LDS, lgkm only) -> epilogue (progressive vmcnt waits).
__global__ __launch_bounds__(256, 3) void main_kernel(
    const float* __restrict__ ent, const float* __restrict__ rel,
    const float* __restrict__ off, const float* __restrict__ b2,
    const int* __restrict__ anchors, const int* __restrict__ rel0,
    const int* __restrict__ p1t, const int* __restrict__ p1r,
    const float* __restrict__ U, const float* __restrict__ V,
    const unsigned short* __restrict__ W2f, float* __restrict__ out)
{
    __shared__ unsigned short w2l[32 * 512];   // 32 KB, B-fragments
    __shared__ float red[4][DD];               // 2 KB reduce scratch
    const int b = blockIdx.x;
    const int tid = threadIdx.x;
    const int w = tid >> 6;
    const int l = tid & 63;
    const int lg = l >> 4;
    const int l15 = l & 15;

    const int aidx = anchors[b];
    const int r0 = rel0[b];
    const int* p1t_b = p1t + (b << 7);
    const int* p1r_b = p1r + (b << 7);

    // ---- prologue: output rows, h_a/b2 fragments, indices, W2->LDS DMA ----
    float o_a = 0.f, o_r = 0.f, o_o = 0.f;
    if (tid < DD) {
        o_a = ent[(size_t)aidx * DD + tid];
        o_r = rel[r0 * DD + tid];
        o_o = off[r0 * DD + tid];
    }
    float hav[8], b2v[8];
    const float* ar = ent + (size_t)aidx * DD + l15;
#pragma unroll
    for (int nt = 0; nt < 8; ++nt) {
        hav[nt] = ar[nt << 4];
        b2v[nt] = b2[(nt << 4) + l15];
    }
    int relA[2];
    int4 tg4[2], rr4[2];
#pragma unroll
    for (int t = 0; t < 2; ++t) {
        const int base = (w << 5) + (t << 4);
        relA[t] = p1r_b[base + l15];
        tg4[t] = *(const int4*)(p1t_b + base + (lg << 2));
        rr4[t] = *(const int4*)(p1r_b + base + (lg << 2));
    }
#pragma unroll
    for (int i = 0; i < 8; ++i) {
        const int chunk = (w << 3) + i;                 // 0..31, 1 KB each
        const unsigned short* g = W2f + chunk * 512 + (l << 3);
        unsigned short* lp = w2l + chunk * 512;         // wave-uniform dest
        __builtin_amdgcn_global_load_lds(
            (const __attribute__((address_space(1))) unsigned int*)g,
            (__attribute__((address_space(3))) unsigned int*)lp, 16, 0, 0);
    }
    asm volatile("s_waitcnt vmcnt(0) lgkmcnt(0)" ::: "memory");
    __builtin_amdgcn_s_barrier();

    float p[8];
#pragma unroll
    for (int nt = 0; nt < 8; ++nt) p[nt] = 0.f;

    const float* Vrow = V + r0 * DD;

#pragma unroll
    for (int t = 0; t < 2; ++t) {
        // --- phase 1: U/V loads + af (waits only U/V; gathers not yet issued) ---
        const float* Urow = U + relA[t] * DD;
        short8 af[4];
#pragma unroll
        for (int kt = 0; kt < 4; ++kt) {
            const int f0 = kt * 32 + lg * 8;
            const float4 u0 = *(const float4*)(Urow + f0);
            const float4 u1 = *(const float4*)(Urow + f0 + 4);
            const float4 v0 = *(const float4*)(Vrow + f0);
            const float4 v1 = *(const float4*)(Vrow + f0 + 4);
            af[kt][0] = f2bf(fmaxf(u0.x + v0.x, 0.f));
            af[kt][1] = f2bf(fmaxf(u0.y + v0.y, 0.f));
            af[kt][2] = f2bf(fmaxf(u0.z + v0.z, 0.f));
            af[kt][3] = f2bf(fmaxf(u0.w + v0.w, 0.f));
            af[kt][4] = f2bf(fmaxf(u1.x + v1.x, 0.f));
            af[kt][5] = f2bf(fmaxf(u1.y + v1.y, 0.f));
            af[kt][6] = f2bf(fmaxf(u1.z + v1.z, 0.f));
            af[kt][7] = f2bf(fmaxf(u1.w + v1.w, 0.f));
        }
        __builtin_amdgcn_sched_barrier(0);

        // --- phase 2: register gathers in fragment layout (stay in flight) ---
        const int tg[4] = {tg4[t].x, tg4[t].y, tg4[t].z, tg4[t].w};
        const int rr[4] = {rr4[t].x, rr4[t].y, rr4[t].z, rr4[t].w};
        float htv[4][8], rvv[4][8];
#pragma unroll
        for (int r2 = 0; r2 < 4; ++r2) {
            const float* gp = ent + (size_t)tg[r2] * DD + l15;
            const float* rp = rel + rr[r2] * DD + l15;
#pragma unroll
            for (int nt = 0; nt < 8; ++nt) {
                htv[r2][nt] = gp[nt << 4];
                rvv[r2][nt] = rp[nt << 4];
            }
        }
        __builtin_amdgcn_sched_barrier(0);

        // --- phase 3: MFMA (A=af regs, B=LDS ds_read; no vmcnt consumption) ---
        f32x4 acc[8];
#pragma unroll
        for (int nt = 0; nt < 8; ++nt) acc[nt] = (f32x4)0.f;
#pragma unroll
        for (int kt = 0; kt < 4; ++kt) {
#pragma unroll
            for (int nt = 0; nt < 8; ++nt) {
                const short8 bf = *(const short8*)(w2l + ((kt << 3) + nt) * 512 + (l << 3));
                acc[nt] = __builtin_amdgcn_mfma_f32_16x16x32_bf16(af[kt], bf, acc[nt], 0, 0, 0);
            }
        }

        // --- phase 4: epilogue (progressive vmcnt waits on gathers) ---
#pragma unroll
        for (int nt = 0; nt < 8; ++nt) {
#pragma unroll
            for (int r2 = 0; r2 < 4; ++r2) {
                const float at = acc[nt][r2] + b2v[nt];
                p[nt] += at * (htv[r2][nt] - hav[nt] - rvv[r2][nt]);
            }
        }
    }

    // ---- cross-lane + cross-wave reduce, output ----
#pragma unroll
    for (int nt = 0; nt < 8; ++nt) {
        p[nt] += __shfl_xor(p[nt], 16);
        p[nt] += __shfl_xor(p[nt], 32);
    }
    if (lg == 0) {
#pragma unroll
        for (int nt = 0; nt < 8; ++nt)
            red[w][(nt << 4) + l15] = p[nt];
    }
    __syncthreads();
    if (tid < DD) {
        const float s = red[0][tid] + red[1][tid] + red[2][tid] + red[3][tid];
        out[(b << 7) + tid] = o_a + o_r + s;
        out[OUT_HALF + (b << 7) + tid] = o_o;
    }
}

extern "C" void kernel_launch(void* const* d_in, const int* in_sizes, int n_in,
                              void* d_out, int out_size, void* d_ws, size_t ws_size,
                              hipStream_t stream) {
    const float* ent  = (const float*)d_in[0];
    const float* rel  = (const float*)d_in[1];
    const float* off  = (const float*)d_in[2];
    const float* W1   = (const float*)d_in[3];
    const float* b1   = (const float*)d_in[4];
    const float* W2   = (const float*)d_in[5];
    const float* b2   = (const float*)d_in[6];
    const int* anchors = (const int*)d_in[7];
    const int* rel0    = (const int*)d_in[8];
    const int* p1t     = (const int*)d_in[9];
    const int* p1r     = (const int*)d_in[10];
    float* out = (float*)d_out;

    float* U = (float*)d_ws;                       // 502*128 f32
    float* V = U + NRELROWS * DD;                  // 502*128 f32
    unsigned short* W2f = (unsigned short*)(V + NRELROWS * DD);  // 128*128 bf16

    precompute_kernel<<<126 + 32, 256, 0, stream>>>(rel, W1, b1, W2, U, V, W2f);
    main_kernel<<<NB, 256, 0, stream>>>(ent, rel, off, b2, anchors, rel0,
                                        p1t, p1r, U, V, W2f, out);
}

// Round 7
// 59.057 us; speedup vs baseline: 1.4968x; 1.4968x over previous
//
#include <hip/hip_runtime.h>

typedef __attribute__((ext_vector_type(8))) short short8;
typedef __attribute__((ext_vector_type(4))) float f32x4;

#define NRELROWS 502
#define NB 2048
#define DD 128
#define OUT_HALF (NB * DD)
#define NPRE 158   // 126 rel-blocks + 32 W2-pack blocks

__device__ __forceinline__ short f2bf(float x) {
    union { float f; unsigned u; } c; c.f = x;
    return (short)((c.u + 0x7FFFu + ((c.u >> 16) & 1u)) >> 16);
}

// Precompute: U[r][d] = sum_f rel[r][f]*W1[d][f]
//             V[r][d] = sum_f rel[r][f]*W1[d][128+f] + b1[d]
//             W2f = W2^T packed in MFMA B-fragment order, bf16
// Also zeroes out[0..OUT_HALF) for the main kernel's atomic accumulation.
__global__ __launch_bounds__(256) void precompute_kernel(
    const float* __restrict__ rel, const float* __restrict__ W1,
    const float* __restrict__ b1, const float* __restrict__ W2,
    float* __restrict__ U, float* __restrict__ V,
    unsigned short* __restrict__ W2f, float* __restrict__ out)
{
    const int bid = blockIdx.x;
    const int tid = threadIdx.x;
    // zero the accumulated output half
    for (int i = bid * 256 + tid; i < OUT_HALF; i += NPRE * 256)
        out[i] = 0.f;

    if (bid < 126) {
        __shared__ float srel[4][DD];
        const int r0 = bid << 2;
        for (int i = tid; i < 512; i += 256) {
            const int r = i >> 7, c = i & 127;
            const int rr = r0 + r;
            srel[r][c] = (rr < NRELROWS) ? rel[rr * DD + c] : 0.f;
        }
        __syncthreads();
        const int half = tid >> 7;      // 0 -> U, 1 -> V
        const int d = tid & 127;
        const float* wrow = W1 + d * 256 + half * 128;
        float a0 = 0.f, a1 = 0.f, a2 = 0.f, a3 = 0.f;
#pragma unroll 8
        for (int f = 0; f < 128; f += 4) {
            const float4 wv = *(const float4*)(wrow + f);
            a0 += srel[0][f]*wv.x + srel[0][f+1]*wv.y + srel[0][f+2]*wv.z + srel[0][f+3]*wv.w;
            a1 += srel[1][f]*wv.x + srel[1][f+1]*wv.y + srel[1][f+2]*wv.z + srel[1][f+3]*wv.w;
            a2 += srel[2][f]*wv.x + srel[2][f+1]*wv.y + srel[2][f+2]*wv.z + srel[2][f+3]*wv.w;
            a3 += srel[3][f]*wv.x + srel[3][f+1]*wv.y + srel[3][f+2]*wv.z + srel[3][f+3]*wv.w;
        }
        float res[4] = {a0, a1, a2, a3};
        const float bb = half ? b1[d] : 0.f;
#pragma unroll
        for (int r = 0; r < 4; ++r) {
            if (r0 + r < NRELROWS) {
                if (half) V[(r0 + r) * DD + d] = res[r] + bb;
                else      U[(r0 + r) * DD + d] = res[r];
            }
        }
    } else if (bid < NPRE) {
        // B-fragment packing: tile = kt*8+nt; within tile: lane ll, slot ii
        // B[f][n] with n = nt*16+(ll&15), f = kt*32+(ll>>4)*8+ii, value = W2[n][f]
        const int tile = bid - 126;   // 0..31
        const int kt = tile >> 3, nt = tile & 7;
#pragma unroll
        for (int e = 0; e < 2; ++e) {
            const int within = tid * 2 + e;          // 0..511
            const int ll = within >> 3, ii = within & 7;
            const int n = nt * 16 + (ll & 15);
            const int f = kt * 32 + (ll >> 4) * 8 + ii;
            W2f[tile * 512 + within] = (unsigned short)f2bf(W2[n * 128 + f]);
        }
    }
}

// Main: 4096 blocks (256 thr, 4 waves). Block bid handles query b=bid>>1,
// neighbor half kh=bid&1 (64 rows). Wave w owns rows [16w,16w+16).
// vmcnt issue-order discipline: W2 DMA -> idx -> ALL compute loads -> ht DMA,
// so af/MFMA's counted waits leave the ht DMA in flight. Raw s_barrier for
// w2l visibility (no vmcnt(0) drain). Results combined via f32 atomicAdd.
__global__ __launch_bounds__(256, 2) void main_kernel(
    const float* __restrict__ ent, const float* __restrict__ rel,
    const float* __restrict__ off, const float* __restrict__ b2,
    const int* __restrict__ anchors, const int* __restrict__ rel0,
    const int* __restrict__ p1t, const int* __restrict__ p1r,
    const float* __restrict__ U, const float* __restrict__ V,
    const unsigned short* __restrict__ W2f, float* __restrict__ out)
{
    __shared__ float ht[64][DD];               // 32 KB; rows 0-3 reused as reduce scratch
    __shared__ unsigned short w2l[32 * 512];   // 32 KB B-fragments
    const int bid = blockIdx.x;
    const int b  = bid >> 1;
    const int kh = bid & 1;
    const int tid = threadIdx.x;
    const int w = tid >> 6;
    const int l = tid & 63;
    const int lg = l >> 4;
    const int l15 = l & 15;
    const int hlf = l >> 5;

    const int* p1t_b = p1t + (b << 7) + (kh << 6);
    const int* p1r_b = p1r + (b << 7) + (kh << 6);

    // ---- phase 0: W2 fragments -> LDS (oldest vmcnt ops) ----
#pragma unroll
    for (int i = 0; i < 8; ++i) {
        const int chunk = (w << 3) + i;                 // 1 KB each
        const unsigned short* g = W2f + chunk * 512 + (l << 3);
        unsigned short* lp = w2l + chunk * 512;
        __builtin_amdgcn_global_load_lds(
            (const __attribute__((address_space(1))) unsigned int*)g,
            (__attribute__((address_space(3))) unsigned int*)lp, 16, 0, 0);
    }
    __builtin_amdgcn_sched_barrier(0);

    // ---- phase 1: index loads ----
    const int aidx = anchors[b];
    const int r0 = rel0[b];
    int rowi[8];
#pragma unroll
    for (int j = 0; j < 8; ++j)
        rowi[j] = p1t_b[(w << 4) + (j << 1) + hlf];
    const int relA = p1r_b[(w << 4) + l15];
    const int4 rr4 = *(const int4*)(p1r_b + (w << 4) + (lg << 2));
    __builtin_amdgcn_sched_barrier(0);

    // ---- phase 2: ALL compute loads (before ht DMA in vmcnt order) ----
    const float* Vrow = V + r0 * DD;
    const float* Urow = U + relA * DD;
    float4 u0[4], u1[4], v0[4], v1[4];
#pragma unroll
    for (int kt = 0; kt < 4; ++kt) {
        const int f0 = kt * 32 + lg * 8;
        u0[kt] = *(const float4*)(Urow + f0);
        u1[kt] = *(const float4*)(Urow + f0 + 4);
        v0[kt] = *(const float4*)(Vrow + f0);
        v1[kt] = *(const float4*)(Vrow + f0 + 4);
    }
    const int rrk[4] = {rr4.x, rr4.y, rr4.z, rr4.w};
    float rv[4][8], hav[8], b2v[8];
#pragma unroll
    for (int r2 = 0; r2 < 4; ++r2) {
        const float* rp = rel + rrk[r2] * DD + l15;
#pragma unroll
        for (int nt = 0; nt < 8; ++nt) rv[r2][nt] = rp[nt << 4];
    }
    const float* ar = ent + (size_t)aidx * DD + l15;
#pragma unroll
    for (int nt = 0; nt < 8; ++nt) {
        hav[nt] = ar[nt << 4];
        b2v[nt] = b2[(nt << 4) + l15];
    }
    float o_a = 0.f, o_r = 0.f, o_o = 0.f;
    if (kh == 0 && tid < DD) {
        o_a = ent[(size_t)aidx * DD + tid];
        o_r = rel[r0 * DD + tid];
        o_o = off[r0 * DD + tid];
    }
    __builtin_amdgcn_sched_barrier(0);

    // ---- phase 3: ht DMA (newest; stays in flight through af+MFMA) ----
#pragma unroll
    for (int j = 0; j < 8; ++j) {
        const float* g = ent + (size_t)rowi[j] * DD + ((l & 31) << 2);
        float* lp = &ht[(w << 4) + (j << 1)][0];  // wave-uniform dest, lane writes +l*16
        __builtin_amdgcn_global_load_lds(
            (const __attribute__((address_space(1))) unsigned int*)g,
            (__attribute__((address_space(3))) unsigned int*)lp, 16, 0, 0);
    }
    __builtin_amdgcn_sched_barrier(0);

    // ---- af compute: counted wait on U/V leaves ht DMA outstanding ----
    short8 af[4];
#pragma unroll
    for (int kt = 0; kt < 4; ++kt) {
        af[kt][0] = f2bf(fmaxf(u0[kt].x + v0[kt].x, 0.f));
        af[kt][1] = f2bf(fmaxf(u0[kt].y + v0[kt].y, 0.f));
        af[kt][2] = f2bf(fmaxf(u0[kt].z + v0[kt].z, 0.f));
        af[kt][3] = f2bf(fmaxf(u0[kt].w + v0[kt].w, 0.f));
        af[kt][4] = f2bf(fmaxf(u1[kt].x + v1[kt].x, 0.f));
        af[kt][5] = f2bf(fmaxf(u1[kt].y + v1[kt].y, 0.f));
        af[kt][6] = f2bf(fmaxf(u1[kt].z + v1[kt].z, 0.f));
        af[kt][7] = f2bf(fmaxf(u1[kt].w + v1[kt].w, 0.f));
    }

    // w2l ready: every wave consumed rowi (phase 3) => its W2 DMA drained.
    __builtin_amdgcn_s_barrier();

    // ---- MFMA: A = af regs, B = LDS ds_read (lgkm only; ht DMA untouched) ----
    f32x4 acc[8];
#pragma unroll
    for (int nt = 0; nt < 8; ++nt) acc[nt] = (f32x4)0.f;
#pragma unroll
    for (int kt = 0; kt < 4; ++kt) {
#pragma unroll
        for (int nt = 0; nt < 8; ++nt) {
            const short8 bf = *(const short8*)(w2l + ((kt << 3) + nt) * 512 + (l << 3));
            acc[nt] = __builtin_amdgcn_mfma_f32_16x16x32_bf16(af[kt], bf, acc[nt], 0, 0, 0);
        }
    }

    // ---- drain ht DMA, then epilogue (all other operands already in regs) ----
    asm volatile("s_waitcnt vmcnt(0)" ::: "memory");
    __builtin_amdgcn_sched_barrier(0);

    float psv[8];
#pragma unroll
    for (int nt = 0; nt < 8; ++nt) {
        const int d = (nt << 4) + l15;
        float p = 0.f;
#pragma unroll
        for (int r2 = 0; r2 < 4; ++r2) {
            const float at = acc[nt][r2] + b2v[nt];      // row 16w + lg*4 + r2
            const float hv = ht[(w << 4) + (lg << 2) + r2][d];
            p += at * (hv - hav[nt] - rv[r2][nt]);
        }
        p += __shfl_xor(p, 16);
        p += __shfl_xor(p, 32);
        psv[nt] = p;
    }

    // ---- cross-wave reduce (reuse ht rows 0-3) + atomic combine ----
    __syncthreads();                  // all waves done reading ht
    float* red = &ht[0][0];           // [4][128]
    if (lg == 0) {
#pragma unroll
        for (int nt = 0; nt < 8; ++nt)
            red[w * DD + (nt << 4) + l15] = psv[nt];
    }
    __syncthreads();
    if (tid < DD) {
        const float s = red[tid] + red[DD + tid] + red[2 * DD + tid] + red[3 * DD + tid];
        if (kh == 0) {
            atomicAdd(out + (b << 7) + tid, o_a + o_r + s);
            out[OUT_HALF + (b << 7) + tid] = o_o;
        } else {
            atomicAdd(out + (b << 7) + tid, s);
        }
    }
}

extern "C" void kernel_launch(void* const* d_in, const int* in_sizes, int n_in,
                              void* d_out, int out_size, void* d_ws, size_t ws_size,
                              hipStream_t stream) {
    const float* ent  = (const float*)d_in[0];
    const float* rel  = (const float*)d_in[1];
    const float* off  = (const float*)d_in[2];
    const float* W1   = (const float*)d_in[3];
    const float* b1   = (const float*)d_in[4];
    const float* W2   = (const float*)d_in[5];
    const float* b2   = (const float*)d_in[6];
    const int* anchors = (const int*)d_in[7];
    const int* rel0    = (const int*)d_in[8];
    const int* p1t     = (const int*)d_in[9];
    const int* p1r     = (const int*)d_in[10];
    float* out = (float*)d_out;

    float* U = (float*)d_ws;                       // 502*128 f32
    float* V = U + NRELROWS * DD;                  // 502*128 f32
    unsigned short* W2f = (unsigned short*)(V + NRELROWS * DD);  // 128*128 bf16

    precompute_kernel<<<NPRE, 256, 0, stream>>>(rel, W1, b1, W2, U, V, W2f, out);
    main_kernel<<<NB * 2, 256, 0, stream>>>(ent, rel, off, b2, anchors, rel0,
                                            p1t, p1r, U, V, W2f, out);
}